// Round 1
// baseline (7074.438 us; speedup 1.0000x reference)
//
#include <hip/hip_runtime.h>

// ============================================================================
// 2-layer LSTM (B=256,T=512,IN=128,H=512) + per-step linear (OUT=128).
// Persistent cooperative kernel, 256 blocks (1/CU) x 512 thr.
//  - 8 batch-groups x 32 wgs; group g owns batches [g*32,g*32+32).
//  - wg w owns h-dims [w*16,w*16+16) of both layers (64 gate rows each).
//  - Weights persist in unified VGPR/AGPR file as fp16 MFMA B-frags (104 regs).
//  - Layers software-pipelined: iteration i computes h1(i) AND h2(i-1) from
//    state exchanged at the previous barrier -> ONE barrier per step.
//  - R6: DIRECT-TO-REGISTER exchange. The MFMA A-frag layout (lane nloc holds
//    8 contiguous halves of batch-row nloc) is exactly hbuf's linear layout,
//    so the R5 restage (hbuf -> LDS -> ds_read_b128) was a redundant hop with
//    4-8 way bank conflicts (ROWP=520 dwords = 4 mod 32; 1.3e8 conflict cyc).
//    Now: A-frags load straight from hbuf via paired 8B relaxed agent atomic
//    loads (same proven coherence path as R5's restage), h1 frags shared by
//    both layers, x frags loaded direct from global (cached, read-only).
//    h1s/h2s/xs LDS buffers and one syncthreads per step are gone.
//  - R6b: hbuf parity double-buffer (write i -> buf[i&1], read i-1 from
//    buf[(i+1)&1]). Reads of parity p for step i-2 finish before the group
//    barrier that precedes any step-i write to parity p => provably race-free
//    (R5 relied on a timing window). Initial zeros via extended host memset.
// ============================================================================

#define Bsz 256
#define Tsz 512
#define INsz 128
#define Hsz 512
#define OUTsz 128

typedef _Float16 half8 __attribute__((ext_vector_type(8)));
typedef float f32x16 __attribute__((ext_vector_type(16)));
typedef float f32x4 __attribute__((ext_vector_type(4)));
typedef unsigned int u32x4 __attribute__((ext_vector_type(4)));
typedef unsigned long long u64;

#define ROWP 520          // halves per 512-wide LDS row (out_gemm only)
#define HBU 65536u        // u32 per hbuf parity buffer (256 KB)

// dynamic LDS layout (bytes) for lstm_seq: gate-partial exchange only
#define GEXA_B 0          // [8 blocks][32 col][36 row] f32 (layer-1 partials)
#define GEXB_B 36864      // [8 blocks][32 col][36 row] f32 (layer-2 partials)
#define LDS1_SIZE 73728
#define LDS2_SIZE 133120  // out_gemm: As[64][520] + Bs[64][520] fp16

__device__ __forceinline__ float sigm(float v)   { return 1.0f / (1.0f + __expf(-v)); }
__device__ __forceinline__ float tanh_f(float v) { return 2.0f / (1.0f + __expf(-2.0f * v)) - 1.0f; }

__device__ __forceinline__ half8 load_w8(const float* src) {
  f32x4 a = *(const f32x4*)src;
  f32x4 b = *(const f32x4*)(src + 4);
  half8 v;
  v[0] = (_Float16)a[0]; v[1] = (_Float16)a[1]; v[2] = (_Float16)a[2]; v[3] = (_Float16)a[3];
  v[4] = (_Float16)b[0]; v[5] = (_Float16)b[1]; v[6] = (_Float16)b[2]; v[7] = (_Float16)b[3];
  return v;
}

__device__ __forceinline__ half8 h8_from(u64 lo, u64 hi) {
  union { u64 q[2]; half8 h; } c;
  c.q[0] = lo; c.q[1] = hi;
  return c.h;
}

// blk MUST be tq*4+kq: epilogue reads blocks [0..3]=tile0(i|f), [4..7]=tile1(g|o)
__device__ __forceinline__ void dump_acc(float* gex, const f32x16& acc, int blk, int nloc, int ktop) {
  #pragma unroll
  for (int r4 = 0; r4 < 4; ++r4) {
    f32x4 v;
    v[0] = acc[r4*4+0]; v[1] = acc[r4*4+1]; v[2] = acc[r4*4+2]; v[3] = acc[r4*4+3];
    // C/D layout 32x32: col=lane&31, row=(reg&3)+8*(reg>>2)+4*(lane>>5); store [col][row]
    *(f32x4*)(gex + (blk*32 + nloc)*36 + r4*8 + ktop*4) = v;
  }
}

__device__ __forceinline__ void epilogue_gates(const float* gex, int eb, int ed,
                                               float bi, float bf, float bg, float bo,
                                               float& c, float& hout) {
  float gi = bi, gf = bf, gg = bg, go = bo;
  #pragma unroll
  for (int q = 0; q < 4; ++q) {             // sum 4 K-quarter partials
    gi += gex[(q*32 + ed)*36 + eb];         // blocks 0..3, cols 0..15  = i
    gf += gex[(q*32 + ed + 16)*36 + eb];    // blocks 0..3, cols 16..31 = f
    gg += gex[((4+q)*32 + ed)*36 + eb];     // blocks 4..7, cols 0..15  = g
    go += gex[((4+q)*32 + ed + 16)*36 + eb];// blocks 4..7, cols 16..31 = o
  }
  float ii = sigm(gi), ff = sigm(gf), ta = tanh_f(gg), oo = sigm(go);
  c = ff * c + ii * ta;
  hout = oo * tanh_f(c);
}

__device__ __forceinline__ unsigned h_bits(float h) {
  union { _Float16 f; unsigned short u; } cv;
  cv.f = (_Float16)h;
  return (unsigned)cv.u;
}

__global__ void __launch_bounds__(512, 2) lstm_seq(
    const float* __restrict__ x,
    const float* __restrict__ Wih1, const float* __restrict__ Whh1,
    const float* __restrict__ bih1, const float* __restrict__ bhh1,
    const float* __restrict__ Wih2, const float* __restrict__ Whh2,
    const float* __restrict__ bih2, const float* __restrict__ bhh2,
    unsigned int* cnt_base,
    unsigned int* __restrict__ hbuf1, unsigned int* __restrict__ hbuf2, // fp16 pairs, 2 parities each
    unsigned int* __restrict__ h2hist)                                  // fp16 pairs
{
  extern __shared__ char lds[];
  float* gexA = (float*)(lds + GEXA_B);
  float* gexB = (float*)(lds + GEXB_B);

  const int tid  = threadIdx.x;
  const int lane = tid & 63;
  const int wv   = tid >> 6;     // 0..7
  const int tq   = wv & 1;       // gate tile (0: i|f, 1: g|o)
  const int kq   = wv >> 1;      // K quarter 0..3
  const int blk  = tq * 4 + kq;  // partial-block index expected by epilogue
  const int g    = blockIdx.x & 7;   // batch group (XCD-local heuristic)
  const int w    = blockIdx.x >> 3;  // member 0..31

  unsigned int* cnt = cnt_base + g * 64;

  const int nloc  = lane & 31;
  const int ktop  = lane >> 5;
  const int gtype = tq * 2 + (nloc >> 4);      // 0:i 1:f 2:g 3:o
  const int wdim  = w * 16 + (nloc & 15);
  const int grow  = gtype * 512 + wdim;

  // ---- persistent weight fragments (B-operand: lane holds W[grow][k..k+8]) ----
  half8 wA[10], wB[16];
  #pragma unroll
  for (int s = 0; s < 8; ++s)
    wA[s] = load_w8(Whh1 + (size_t)grow * Hsz + (kq*8 + s)*16 + ktop*8);
  #pragma unroll
  for (int s = 0; s < 2; ++s)
    wA[8+s] = load_w8(Wih1 + (size_t)grow * INsz + kq*32 + s*16 + ktop*8);
  #pragma unroll
  for (int s = 0; s < 8; ++s)
    wB[s] = load_w8(Wih2 + (size_t)grow * Hsz + (kq*8 + s)*16 + ktop*8);
  #pragma unroll
  for (int s = 0; s < 8; ++s)
    wB[8+s] = load_w8(Whh2 + (size_t)grow * Hsz + (kq*8 + s)*16 + ktop*8);

  // ---- epilogue ownership: ed = dim-local (adjacent lanes), eb = batch ----
  const int ed = tid & 15;
  const int eb = tid >> 4;           // 0..31
  const int edim = w * 16 + ed;
  float bi1 = bih1[0*512+edim] + bhh1[0*512+edim];
  float bf1 = bih1[1*512+edim] + bhh1[1*512+edim];
  float bg1 = bih1[2*512+edim] + bhh1[2*512+edim];
  float bo1 = bih1[3*512+edim] + bhh1[3*512+edim];
  float bi2 = bih2[0*512+edim] + bhh2[0*512+edim];
  float bf2 = bih2[1*512+edim] + bhh2[1*512+edim];
  float bg2 = bih2[2*512+edim] + bhh2[2*512+edim];
  float bo2 = bih2[3*512+edim] + bhh2[3*512+edim];
  float c1 = 0.0f, c2 = 0.0f;

  // per-lane fragment addressing into hbuf (u64 granularity: 128 u64 per row)
  const int rowq = (g*32 + nloc) * 128;
  const int colq = kq*32 + ktop*2;   // + s*4 per K-subtile

  // iteration i: layer-1 computes h1(i) (i<T), layer-2 computes h2(i-1) (i>0)
  for (int i = 0; i <= Tsz; ++i) {
    const bool doA = (i < Tsz);
    const bool doB = (i > 0);

    // parity double-buffer: write i -> [i&1]; read h1(i-1) from [(i+1)&1],
    // h2(i-2) from [i&1] (== (i-2)&1).
    const u64* rb1 = (const u64*)(hbuf1 + ((i+1)&1)*HBU);
    const u64* rb2 = (const u64*)(hbuf2 + (i&1)*HBU);
    unsigned* wb1 = hbuf1 + (i&1)*HBU;
    unsigned* wb2 = hbuf2 + ((i+1)&1)*HBU;

    // ---- direct A-fragment loads: h1(i-1), h2(i-2) -> registers ----
    u64 a1q[16], a2q[16];
    #pragma unroll
    for (int s = 0; s < 8; ++s) {
      const u64* p = rb1 + rowq + colq + s*4;
      a1q[2*s]   = __hip_atomic_load(p,     __ATOMIC_RELAXED, __HIP_MEMORY_SCOPE_AGENT);
      a1q[2*s+1] = __hip_atomic_load(p + 1, __ATOMIC_RELAXED, __HIP_MEMORY_SCOPE_AGENT);
    }
    if (doB) {
      #pragma unroll
      for (int s = 0; s < 8; ++s) {
        const u64* p = rb2 + rowq + colq + s*4;
        a2q[2*s]   = __hip_atomic_load(p,     __ATOMIC_RELAXED, __HIP_MEMORY_SCOPE_AGENT);
        a2q[2*s+1] = __hip_atomic_load(p + 1, __ATOMIC_RELAXED, __HIP_MEMORY_SCOPE_AGENT);
      }
    }
    half8 ax0, ax1;
    if (doA) {  // x frags direct from global (read-only, cached, L3-resident)
      const float* xp = x + ((size_t)(g*32 + nloc) * Tsz + i) * INsz + kq*32 + ktop*8;
      ax0 = load_w8(xp);
      ax1 = load_w8(xp + 16);
    }

    if (doA) {  // gates1 = Whh1 @ h1(i-1) + Wih1 @ x_i
      f32x16 acc;
      #pragma unroll
      for (int k = 0; k < 16; ++k) acc[k] = 0.0f;
      #pragma unroll
      for (int s = 0; s < 8; ++s)
        acc = __builtin_amdgcn_mfma_f32_32x32x16_f16(h8_from(a1q[2*s], a1q[2*s+1]), wA[s], acc, 0, 0, 0);
      acc = __builtin_amdgcn_mfma_f32_32x32x16_f16(ax0, wA[8], acc, 0, 0, 0);
      acc = __builtin_amdgcn_mfma_f32_32x32x16_f16(ax1, wA[9], acc, 0, 0, 0);
      dump_acc(gexA, acc, blk, nloc, ktop);
    }
    if (doB) {  // gates2 = Wih2 @ h1(i-1) + Whh2 @ h2(i-2)
      f32x16 acc;
      #pragma unroll
      for (int k = 0; k < 16; ++k) acc[k] = 0.0f;
      #pragma unroll
      for (int s = 0; s < 8; ++s)
        acc = __builtin_amdgcn_mfma_f32_32x32x16_f16(h8_from(a1q[2*s], a1q[2*s+1]), wB[s], acc, 0, 0, 0);
      #pragma unroll
      for (int s = 0; s < 8; ++s)
        acc = __builtin_amdgcn_mfma_f32_32x32x16_f16(h8_from(a2q[2*s], a2q[2*s+1]), wB[8+s], acc, 0, 0, 0);
      dump_acc(gexB, acc, blk, nloc, ktop);
    }
    __syncthreads();   // gex partials visible

    // ---- epilogues: pack 2 fp16 per dword, sc1 write-through stores ----
    if (doA) {
      float h;
      epilogue_gates(gexA, eb, ed, bi1, bf1, bg1, bo1, c1, h);
      unsigned lo = h_bits(h);
      unsigned hi = __shfl_down(lo, 1, 64);
      if (!(tid & 1))
        __hip_atomic_store(wb1 + (((g*32 + eb)*Hsz + w*16 + ed) >> 1),
                           lo | (hi << 16), __ATOMIC_RELAXED, __HIP_MEMORY_SCOPE_AGENT);
    }
    if (doB) {
      float h;
      epilogue_gates(gexB, eb, ed, bi2, bf2, bg2, bo2, c2, h);
      unsigned lo = h_bits(h);
      unsigned hi = __shfl_down(lo, 1, 64);
      if (!(tid & 1)) {
        unsigned v = lo | (hi << 16);
        __hip_atomic_store(wb2 + (((g*32 + eb)*Hsz + w*16 + ed) >> 1),
                           v, __ATOMIC_RELAXED, __HIP_MEMORY_SCOPE_AGENT);
        // nontemporal plain store; visibility to out_gemm via kernel boundary
        __builtin_nontemporal_store(v,
            h2hist + ((((size_t)(g*32 + eb)*Tsz + (i-1))*Hsz + w*16 + ed) >> 1));
      }
    }
    if (i == Tsz) break;   // last h2 stored; no further exchange needed

    // ---- fence-free group barrier (R5 semantics, proven) ----
    __syncthreads();   // vmcnt(0): every wave's sc1 stores acked at coherence
                       // point before any wave proceeds => release semantics
    if (tid == 0) {
      __hip_atomic_fetch_add(cnt, 1u, __ATOMIC_RELAXED, __HIP_MEMORY_SCOPE_AGENT);
      const unsigned target = (unsigned)(i + 1) * 32u;
      while (__hip_atomic_load(cnt, __ATOMIC_RELAXED, __HIP_MEMORY_SCOPE_AGENT) < target)
        __builtin_amdgcn_s_sleep(1);
    }
    __syncthreads();
    // next-iteration fragment loads follow immediately (direct to registers)
  }
}

// ======================= final linear: out = H2 @ Wlin^T + b =================
__global__ void __launch_bounds__(256) out_gemm(
    const _Float16* __restrict__ h2hist, const float* __restrict__ Wlin,
    const float* __restrict__ blin, float* __restrict__ out)
{
  extern __shared__ char lds[];
  _Float16* As = (_Float16*)lds;              // [64][520]
  _Float16* Bs = (_Float16*)(lds + 66560);    // [64][520]
  const int tid = threadIdx.x;
  const int bt0 = blockIdx.x * 64;
  const int n0  = blockIdx.y * 64;

  {
    const int r = tid >> 2, k0 = (tid & 3) * 128;
    const u32x4* src = (const u32x4*)(h2hist + (size_t)(bt0 + r) * Hsz + k0);
    #pragma unroll
    for (int i = 0; i < 16; ++i)
      *(u32x4*)(As + r*ROWP + k0 + i*8) = src[i];
  }
  {
    const int n = tid >> 2, k0 = (tid & 3) * 128;
    const float* src = Wlin + (size_t)(n0 + n) * Hsz + k0;
    #pragma unroll
    for (int i = 0; i < 16; ++i)
      *(half8*)(Bs + n*ROWP + k0 + i*8) = load_w8(src + i*8);
  }
  __syncthreads();

  const int lane = tid & 63;
  const int wvid = tid >> 6;           // M-tile 0..3
  const int mrow = wvid*16 + (lane & 15);
  const int kt   = lane >> 4;          // 0..3
  f32x4 acc[4];
  #pragma unroll
  for (int nt = 0; nt < 4; ++nt) { acc[nt][0]=0; acc[nt][1]=0; acc[nt][2]=0; acc[nt][3]=0; }

  #pragma unroll
  for (int ks = 0; ks < 16; ++ks) {
    half8 a = *(const half8*)(As + mrow*ROWP + ks*32 + kt*8);
    #pragma unroll
    for (int nt = 0; nt < 4; ++nt) {
      half8 b = *(const half8*)(Bs + (nt*16 + (lane & 15))*ROWP + ks*32 + kt*8);
      acc[nt] = __builtin_amdgcn_mfma_f32_16x16x32_f16(a, b, acc[nt], 0, 0, 0);
    }
  }
  #pragma unroll
  for (int nt = 0; nt < 4; ++nt) {
    const int n = n0 + nt*16 + (lane & 15);
    const float bb = blin[n];
    #pragma unroll
    for (int r = 0; r < 4; ++r) {
      const int row = bt0 + wvid*16 + (lane >> 4)*4 + r;  // C/D: col=lane&15, row=quad*4+reg
      out[(size_t)row * OUTsz + n] = acc[nt][r] + bb;
    }
  }
}

extern "C" void kernel_launch(void* const* d_in, const int* in_sizes, int n_in,
                              void* d_out, int out_size, void* d_ws, size_t ws_size,
                              hipStream_t stream) {
  const float* x    = (const float*)d_in[0];
  const float* Wih1 = (const float*)d_in[2];
  const float* Whh1 = (const float*)d_in[3];
  const float* bih1 = (const float*)d_in[4];
  const float* bhh1 = (const float*)d_in[5];
  const float* Wih2 = (const float*)d_in[6];
  const float* Whh2 = (const float*)d_in[7];
  const float* bih2 = (const float*)d_in[8];
  const float* bhh2 = (const float*)d_in[9];
  const float* Wlin = (const float*)d_in[10];
  const float* blin = (const float*)d_in[11];
  float* out = (float*)d_out;

  char* ws = (char*)d_ws;
  unsigned int* cnt    = (unsigned int*)ws;               // 8 x 256B counters
  unsigned int* hbuf1  = (unsigned int*)(ws + 4096);      // 2 parities x 256 KB
  unsigned int* hbuf2  = (unsigned int*)(ws + 4096 + 524288);
  unsigned int* h2hist = (unsigned int*)(ws + 2097152);   // 64 MB (fp16 pairs)

  // zero barrier counters + both parities of both h-exchange buffers
  hipMemsetAsync(ws, 0, 4096 + 1048576, stream);

  hipFuncSetAttribute((const void*)lstm_seq, hipFuncAttributeMaxDynamicSharedMemorySize, LDS1_SIZE);
  hipFuncSetAttribute((const void*)out_gemm, hipFuncAttributeMaxDynamicSharedMemorySize, LDS2_SIZE);

  void* args[] = { (void*)&x, (void*)&Wih1, (void*)&Whh1, (void*)&bih1, (void*)&bhh1,
                   (void*)&Wih2, (void*)&Whh2, (void*)&bih2, (void*)&bhh2,
                   (void*)&cnt, (void*)&hbuf1, (void*)&hbuf2, (void*)&h2hist };
  hipLaunchCooperativeKernel((const void*)lstm_seq, dim3(256), dim3(512), args,
                             (unsigned int)LDS1_SIZE, stream);

  out_gemm<<<dim3(2048, 2), dim3(256), LDS2_SIZE, stream>>>((const _Float16*)h2hist, Wlin, blin, out);
}

// Round 3
// 2767.543 us; speedup vs baseline: 2.5562x; 2.5562x over previous
//
#include <hip/hip_runtime.h>

// ============================================================================
// 2-layer LSTM (B=256,T=512,IN=128,H=512) + per-step linear (OUT=128).
// Persistent cooperative kernel, 256 blocks (1/CU) x 512 thr.
//  - R8: XCD-LOCAL DATA exchange + AGENT-SCOPE (hang-proof) barrier.
//    * Groups formed by PHYSICAL XCD: block reads XCC_ID via
//      __builtin_amdgcn_s_getreg (hwreg 20, offset 0, width 4) and claims
//      slot w in its XCD's roster (one agent atomic at init). 144KB LDS
//      forces 1 block/CU; cooperative co-residency of 256 blocks on 256 CUs
//      => exactly 32 blocks/XCD => roster partition sound.
//    * h stores: PLAIN stores (write-through L1 -> dirty in local L2; the
//      vmcnt(0) inside __syncthreads acks them at L2 BEFORE tid0's counter
//      add => release).
//    * restage: coalesced 8B sc0 loads (bypass stale L1, hit own L2) ->
//      XOR-swizzled LDS (conflict-free ds_read_b128) -> MFMA frags.
//    * barrier: R5's PROVEN agent-scope fetch_add + agent relaxed poll.
//      Liveness never depends on the XCD-grouping assumption: if grouping
//      were wrong we fail absmax (stale data), we do NOT hang. R7 coupled
//      barrier liveness to grouping (L2-local poll) -> unfalsifiable hang.
//  - R6 lesson kept: exchange loads stay COALESCED (per-lane frag gather was
//    16x request-amplified at the cache and regressed).
//  - Layers software-pipelined: iteration i computes h1(i) AND h2(i-1);
//    layer-2 reuses layer-1's h1 fragments from REGISTERS (-8 ds_reads).
//  - Parity double-buffered hbuf (race-free by barrier ordering).
// ============================================================================

#define Bsz 256
#define Tsz 512
#define INsz 128
#define Hsz 512
#define OUTsz 128

typedef _Float16 half8 __attribute__((ext_vector_type(8)));
typedef float f32x16 __attribute__((ext_vector_type(16)));
typedef float f32x4 __attribute__((ext_vector_type(4)));
typedef unsigned int u32x4 __attribute__((ext_vector_type(4)));
typedef unsigned long long u64;

#define ROWP 520          // halves per 512-wide LDS row (out_gemm only)
#define HBU 65536u        // u32 per hbuf parity buffer (256 KB)

// dynamic LDS layout (bytes) for lstm_seq
#define H1S_B 0           // [32][512] fp16, XOR-swizzled (byte ^= row<<4)
#define H2S_B 32768       // [32][512] fp16, swizzled
#define XS_B  65536       // [32][128] fp16, swizzled (byte ^= (row&15)<<4)
#define GEXA_B 73728      // [8 blocks][32 col][36 row] f32 (layer-1 partials)
#define GEXB_B 110592     // [8 blocks][32 col][36 row] f32 (layer-2 partials)
#define LDS1_SIZE 147456  // 144KB > 80KB => hard cap 1 block/CU (roster proof)
#define LDS2_SIZE 133120  // out_gemm: As[64][520] + Bs[64][520] fp16

__device__ __forceinline__ float sigm(float v)   { return 1.0f / (1.0f + __expf(-v)); }
__device__ __forceinline__ float tanh_f(float v) { return 2.0f / (1.0f + __expf(-2.0f * v)) - 1.0f; }

__device__ __forceinline__ half8 load_w8(const float* src) {
  f32x4 a = *(const f32x4*)src;
  f32x4 b = *(const f32x4*)(src + 4);
  half8 v;
  v[0] = (_Float16)a[0]; v[1] = (_Float16)a[1]; v[2] = (_Float16)a[2]; v[3] = (_Float16)a[3];
  v[4] = (_Float16)b[0]; v[5] = (_Float16)b[1]; v[6] = (_Float16)b[2]; v[7] = (_Float16)b[3];
  return v;
}

// blk MUST be tq*4+kq: epilogue reads blocks [0..3]=tile0(i|f), [4..7]=tile1(g|o)
__device__ __forceinline__ void dump_acc(float* gex, const f32x16& acc, int blk, int nloc, int ktop) {
  #pragma unroll
  for (int r4 = 0; r4 < 4; ++r4) {
    f32x4 v;
    v[0] = acc[r4*4+0]; v[1] = acc[r4*4+1]; v[2] = acc[r4*4+2]; v[3] = acc[r4*4+3];
    // C/D layout 32x32: col=lane&31, row=(reg&3)+8*(reg>>2)+4*(lane>>5); store [col][row]
    *(f32x4*)(gex + (blk*32 + nloc)*36 + r4*8 + ktop*4) = v;
  }
}

__device__ __forceinline__ void epilogue_gates(const float* gex, int eb, int ed,
                                               float bi, float bf, float bg, float bo,
                                               float& c, float& hout) {
  float gi = bi, gf = bf, gg = bg, go = bo;
  #pragma unroll
  for (int q = 0; q < 4; ++q) {             // sum 4 K-quarter partials
    gi += gex[(q*32 + ed)*36 + eb];         // blocks 0..3, cols 0..15  = i
    gf += gex[(q*32 + ed + 16)*36 + eb];    // blocks 0..3, cols 16..31 = f
    gg += gex[((4+q)*32 + ed)*36 + eb];     // blocks 4..7, cols 0..15  = g
    go += gex[((4+q)*32 + ed + 16)*36 + eb];// blocks 4..7, cols 16..31 = o
  }
  float ii = sigm(gi), ff = sigm(gf), ta = tanh_f(gg), oo = sigm(go);
  c = ff * c + ii * ta;
  hout = oo * tanh_f(c);
}

__device__ __forceinline__ unsigned h_bits(float h) {
  union { _Float16 f; unsigned short u; } cv;
  cv.f = (_Float16)h;
  return (unsigned)cv.u;
}

// sc0 load: bypass L1, read own XCD's L2 (where group members' plain stores land)
__device__ __forceinline__ u64 load_u64_sc0(const u64* p) {
  u64 v;
  asm volatile("global_load_dwordx2 %0, %1, off sc0" : "=v"(v) : "v"(p));
  return v;
}

__global__ void __launch_bounds__(512, 2) lstm_seq(
    const float* __restrict__ x,
    const float* __restrict__ Wih1, const float* __restrict__ Whh1,
    const float* __restrict__ bih1, const float* __restrict__ bhh1,
    const float* __restrict__ Wih2, const float* __restrict__ Whh2,
    const float* __restrict__ bih2, const float* __restrict__ bhh2,
    unsigned int* cnt_base,
    unsigned int* __restrict__ hbuf1, unsigned int* __restrict__ hbuf2, // fp16 pairs, 2 parities
    unsigned int* __restrict__ h2hist)                                  // fp16 pairs
{
  extern __shared__ char lds[];
  float* gexA = (float*)(lds + GEXA_B);
  float* gexB = (float*)(lds + GEXB_B);
  int* s_gw = (int*)(lds + GEXA_B);   // reuse gexA space for the roster handoff

  const int tid  = threadIdx.x;
  const int lane = tid & 63;
  const int wv   = tid >> 6;     // 0..7
  const int tq   = wv & 1;       // gate tile (0: i|f, 1: g|o)
  const int kq   = wv >> 1;      // K quarter 0..3
  const int blk  = tq * 4 + kq;  // partial-block index expected by epilogue

  // ---- dynamic XCD grouping: g = physical XCD, w = roster slot ----
  if (tid == 0) {
    // s_getreg_b32 hwreg(HW_REG_XCC_ID=20, offset=0, size=4): imm = (4-1)<<11 | 0<<6 | 20
    unsigned xcd = __builtin_amdgcn_s_getreg(6164) & 7u;
    unsigned slot = __hip_atomic_fetch_add(cnt_base + 512 + xcd, 1u,
                                           __ATOMIC_RELAXED, __HIP_MEMORY_SCOPE_AGENT);
    s_gw[0] = (int)xcd;
    s_gw[1] = (int)(slot & 31u);
  }
  __syncthreads();
  const int g = s_gw[0];             // batch group == physical XCD
  const int w = s_gw[1];             // member 0..31 (owns h-dims w*16..w*16+15)
  __syncthreads();                   // everyone read s_gw before gexA reuse

  unsigned int* cnt = cnt_base + g * 64;

  const int nloc  = lane & 31;
  const int ktop  = lane >> 5;
  const int gtype = tq * 2 + (nloc >> 4);      // 0:i 1:f 2:g 3:o
  const int wdim  = w * 16 + (nloc & 15);
  const int grow  = gtype * 512 + wdim;

  // ---- persistent weight fragments (B-operand: lane holds W[grow][k..k+8]) ----
  half8 wA[10], wB[16];
  #pragma unroll
  for (int s = 0; s < 8; ++s)
    wA[s] = load_w8(Whh1 + (size_t)grow * Hsz + (kq*8 + s)*16 + ktop*8);
  #pragma unroll
  for (int s = 0; s < 2; ++s)
    wA[8+s] = load_w8(Wih1 + (size_t)grow * INsz + kq*32 + s*16 + ktop*8);
  #pragma unroll
  for (int s = 0; s < 8; ++s)
    wB[s] = load_w8(Wih2 + (size_t)grow * Hsz + (kq*8 + s)*16 + ktop*8);
  #pragma unroll
  for (int s = 0; s < 8; ++s)
    wB[8+s] = load_w8(Whh2 + (size_t)grow * Hsz + (kq*8 + s)*16 + ktop*8);

  // ---- epilogue ownership: ed = dim-local (adjacent lanes), eb = batch ----
  const int ed = tid & 15;
  const int eb = tid >> 4;           // 0..31
  const int edim = w * 16 + ed;
  float bi1 = bih1[0*512+edim] + bhh1[0*512+edim];
  float bf1 = bih1[1*512+edim] + bhh1[1*512+edim];
  float bg1 = bih1[2*512+edim] + bhh1[2*512+edim];
  float bo1 = bih1[3*512+edim] + bhh1[3*512+edim];
  float bi2 = bih2[0*512+edim] + bhh2[0*512+edim];
  float bf2 = bih2[1*512+edim] + bhh2[1*512+edim];
  float bg2 = bih2[2*512+edim] + bhh2[2*512+edim];
  float bo2 = bih2[3*512+edim] + bhh2[3*512+edim];
  float c1 = 0.0f, c2 = 0.0f;

  const int stg_m = tid >> 4, stg_ch = tid & 15;   // x staging: row, 16B chunk
  const int fragC = (kq*8)*32 + ktop*16;           // frag col byte base (s adds 32)
  const int xC    = kq*64 + ktop*16;               // x frag col byte base (s adds 32)

  // iteration i: layer-1 computes h1(i) (i<T), layer-2 computes h2(i-1) (i>0)
  for (int i = 0; i <= Tsz; ++i) {
    const bool doA = (i < Tsz);
    const bool doB = (i > 0);

    // parity double-buffer: write h1(i) -> [i&1], h2(i-1) -> [(i+1)&1];
    // read h1(i-1) from [(i+1)&1], h2(i-2) from [i&1].
    const u64* pb1 = (const u64*)hbuf1 + (size_t)((i+1)&1)*32768 + g*4096;
    const u64* pb2 = (const u64*)hbuf2 + (size_t)(i&1)*32768 + g*4096;
    unsigned* wb1 = hbuf1 + (i&1)*HBU;
    unsigned* wb2 = hbuf2 + ((i+1)&1)*HBU;

    // ---- issue coalesced sc0 restage loads (own-XCD L2 hits) ----
    u64 q1[8], q2[8];
    #pragma unroll
    for (int j = 0; j < 8; ++j)
      q1[j] = load_u64_sc0(pb1 + j*512 + tid);
    if (doB) {
      #pragma unroll
      for (int j = 0; j < 8; ++j)
        q2[j] = load_u64_sc0(pb2 + j*512 + tid);
    }
    // ---- x stage overlaps the sc0 load latency ----
    if (doA) {
      const float* src = x + ((size_t)(g*32 + stg_m) * Tsz + i) * INsz + stg_ch*8;
      *(half8*)(lds + XS_B + stg_m*256 + ((stg_ch*16) ^ ((stg_m & 15) << 4))) = load_w8(src);
    }
    asm volatile("s_waitcnt vmcnt(0)" ::: "memory");
    __builtin_amdgcn_sched_barrier(0);
    // ---- swizzled LDS writes ----
    #pragma unroll
    for (int j = 0; j < 8; ++j) {
      const int L = j*512 + tid, r = L >> 7, b = (L & 127) * 8;
      *(u64*)(lds + H1S_B + r*1024 + (b ^ (r << 4))) = q1[j];
    }
    if (doB) {
      #pragma unroll
      for (int j = 0; j < 8; ++j) {
        const int L = j*512 + tid, r = L >> 7, b = (L & 127) * 8;
        *(u64*)(lds + H2S_B + r*1024 + (b ^ (r << 4))) = q2[j];
      }
    }
    __syncthreads();   // staged h1/h2/x ready

    // ---- h1 fragments once from LDS (swizzled, conflict-free), reused by both layers ----
    half8 a1[8];
    #pragma unroll
    for (int s = 0; s < 8; ++s)
      a1[s] = *(const half8*)(lds + H1S_B + nloc*1024 + ((fragC + s*32) ^ (nloc << 4)));

    if (doA) {  // gates1 = Whh1 @ h1(i-1) + Wih1 @ x_i
      f32x16 acc;
      #pragma unroll
      for (int k = 0; k < 16; ++k) acc[k] = 0.0f;
      #pragma unroll
      for (int s = 0; s < 8; ++s)
        acc = __builtin_amdgcn_mfma_f32_32x32x16_f16(a1[s], wA[s], acc, 0, 0, 0);
      #pragma unroll
      for (int s = 0; s < 2; ++s) {
        half8 ax = *(const half8*)(lds + XS_B + nloc*256 + ((xC + s*32) ^ ((nloc & 15) << 4)));
        acc = __builtin_amdgcn_mfma_f32_32x32x16_f16(ax, wA[8+s], acc, 0, 0, 0);
      }
      dump_acc(gexA, acc, blk, nloc, ktop);
    }
    if (doB) {  // gates2 = Wih2 @ h1(i-1) + Whh2 @ h2(i-2)
      f32x16 acc;
      #pragma unroll
      for (int k = 0; k < 16; ++k) acc[k] = 0.0f;
      #pragma unroll
      for (int s = 0; s < 8; ++s)
        acc = __builtin_amdgcn_mfma_f32_32x32x16_f16(a1[s], wB[s], acc, 0, 0, 0);
      #pragma unroll
      for (int s = 0; s < 8; ++s) {
        half8 a2 = *(const half8*)(lds + H2S_B + nloc*1024 + ((fragC + s*32) ^ (nloc << 4)));
        acc = __builtin_amdgcn_mfma_f32_32x32x16_f16(a2, wB[8+s], acc, 0, 0, 0);
      }
      dump_acc(gexB, acc, blk, nloc, ktop);
    }
    __syncthreads();   // partials visible

    // ---- epilogues: pack 2 fp16 per dword, PLAIN stores (dirty in local L2) ----
    if (doA) {
      float h;
      epilogue_gates(gexA, eb, ed, bi1, bf1, bg1, bo1, c1, h);
      unsigned lo = h_bits(h);
      unsigned hi = __shfl_down(lo, 1, 64);
      if (!(tid & 1))
        wb1[((g*32 + eb)*Hsz + w*16 + ed) >> 1] = lo | (hi << 16);
    }
    if (doB) {
      float h;
      epilogue_gates(gexB, eb, ed, bi2, bf2, bg2, bo2, c2, h);
      unsigned lo = h_bits(h);
      unsigned hi = __shfl_down(lo, 1, 64);
      if (!(tid & 1)) {
        unsigned v = lo | (hi << 16);
        wb2[((g*32 + eb)*Hsz + w*16 + ed) >> 1] = v;
        // nontemporal plain store; visibility to out_gemm via kernel boundary
        __builtin_nontemporal_store(v,
            h2hist + ((((size_t)(g*32 + eb)*Tsz + (i-1))*Hsz + w*16 + ed) >> 1));
      }
    }
    if (i == Tsz) break;   // last h2 stored; no further exchange needed

    // ---- group barrier: agent-scope (hang-proof, R5-proven) ----
    __syncthreads();   // vmcnt(0): every wave's plain stores acked at local L2
                       // before tid0's counter add => release
    if (tid == 0) {
      __hip_atomic_fetch_add(cnt, 1u, __ATOMIC_RELAXED, __HIP_MEMORY_SCOPE_AGENT);
      const unsigned target = (unsigned)(i + 1) * 32u;
      while (__hip_atomic_load(cnt, __ATOMIC_RELAXED, __HIP_MEMORY_SCOPE_AGENT) < target)
        __builtin_amdgcn_s_sleep(1);
    }
    __syncthreads();
  }
}

// ======================= final linear: out = H2 @ Wlin^T + b =================
__global__ void __launch_bounds__(256) out_gemm(
    const _Float16* __restrict__ h2hist, const float* __restrict__ Wlin,
    const float* __restrict__ blin, float* __restrict__ out)
{
  extern __shared__ char lds[];
  _Float16* As = (_Float16*)lds;              // [64][520]
  _Float16* Bs = (_Float16*)(lds + 66560);    // [64][520]
  const int tid = threadIdx.x;
  const int bt0 = blockIdx.x * 64;
  const int n0  = blockIdx.y * 64;

  {
    const int r = tid >> 2, k0 = (tid & 3) * 128;
    const u32x4* src = (const u32x4*)(h2hist + (size_t)(bt0 + r) * Hsz + k0);
    #pragma unroll
    for (int i = 0; i < 16; ++i)
      *(u32x4*)(As + r*ROWP + k0 + i*8) = src[i];
  }
  {
    const int n = tid >> 2, k0 = (tid & 3) * 128;
    const float* src = Wlin + (size_t)(n0 + n) * Hsz + k0;
    #pragma unroll
    for (int i = 0; i < 16; ++i)
      *(half8*)(Bs + n*ROWP + k0 + i*8) = load_w8(src + i*8);
  }
  __syncthreads();

  const int lane = tid & 63;
  const int wvid = tid >> 6;           // M-tile 0..3
  const int mrow = wvid*16 + (lane & 15);
  const int kt   = lane >> 4;          // 0..3
  f32x4 acc[4];
  #pragma unroll
  for (int nt = 0; nt < 4; ++nt) { acc[nt][0]=0; acc[nt][1]=0; acc[nt][2]=0; acc[nt][3]=0; }

  #pragma unroll
  for (int ks = 0; ks < 16; ++ks) {
    half8 a = *(const half8*)(As + mrow*ROWP + ks*32 + kt*8);
    #pragma unroll
    for (int nt = 0; nt < 4; ++nt) {
      half8 b = *(const half8*)(Bs + (nt*16 + (lane & 15))*ROWP + ks*32 + kt*8);
      acc[nt] = __builtin_amdgcn_mfma_f32_16x16x32_f16(a, b, acc[nt], 0, 0, 0);
    }
  }
  #pragma unroll
  for (int nt = 0; nt < 4; ++nt) {
    const int n = n0 + nt*16 + (lane & 15);
    const float bb = blin[n];
    #pragma unroll
    for (int r = 0; r < 4; ++r) {
      const int row = bt0 + wvid*16 + (lane >> 4)*4 + r;  // C/D: col=lane&15, row=quad*4+reg
      out[(size_t)row * OUTsz + n] = acc[nt][r] + bb;
    }
  }
}

extern "C" void kernel_launch(void* const* d_in, const int* in_sizes, int n_in,
                              void* d_out, int out_size, void* d_ws, size_t ws_size,
                              hipStream_t stream) {
  const float* x    = (const float*)d_in[0];
  const float* Wih1 = (const float*)d_in[2];
  const float* Whh1 = (const float*)d_in[3];
  const float* bih1 = (const float*)d_in[4];
  const float* bhh1 = (const float*)d_in[5];
  const float* Wih2 = (const float*)d_in[6];
  const float* Whh2 = (const float*)d_in[7];
  const float* bih2 = (const float*)d_in[8];
  const float* bhh2 = (const float*)d_in[9];
  const float* Wlin = (const float*)d_in[10];
  const float* blin = (const float*)d_in[11];
  float* out = (float*)d_out;

  char* ws = (char*)d_ws;
  unsigned int* cnt    = (unsigned int*)ws;               // 8 grp x 256B counters; roster at +2048
  unsigned int* hbuf1  = (unsigned int*)(ws + 4096);      // 2 parities x 256 KB
  unsigned int* hbuf2  = (unsigned int*)(ws + 4096 + 524288);
  unsigned int* h2hist = (unsigned int*)(ws + 2097152);   // 128 MB (fp16 pairs)

  // zero barrier counters + roster + both parities of both h-exchange buffers
  hipMemsetAsync(ws, 0, 4096 + 1048576, stream);

  hipFuncSetAttribute((const void*)lstm_seq, hipFuncAttributeMaxDynamicSharedMemorySize, LDS1_SIZE);
  hipFuncSetAttribute((const void*)out_gemm, hipFuncAttributeMaxDynamicSharedMemorySize, LDS2_SIZE);

  void* args[] = { (void*)&x, (void*)&Wih1, (void*)&Whh1, (void*)&bih1, (void*)&bhh1,
                   (void*)&Wih2, (void*)&Whh2, (void*)&bih2, (void*)&bhh2,
                   (void*)&cnt, (void*)&hbuf1, (void*)&hbuf2, (void*)&h2hist };
  hipLaunchCooperativeKernel((const void*)lstm_seq, dim3(256), dim3(512), args,
                             (unsigned int)LDS1_SIZE, stream);

  out_gemm<<<dim3(2048, 2), dim3(256), LDS2_SIZE, stream>>>((const _Float16*)h2hist, Wlin, blin, out);
}